// Round 9
// baseline (127.765 us; speedup 1.0000x reference)
//
#include <hip/hip_runtime.h>
#include <math.h>

// NormalLoss: for each template vertex (M=6890), take the K=15 scan points
// (N=20000) with LARGEST distance, among them pick the min-angle normal
// match, loss = mean ||sv[sel]-tv||.
//
// Round-15: EXACT R0 restoration (proven 30.5 us, absmax 0.0) + two safe
// orthogonal deltas. Ledger (binding):
//  * pure 256-bucket fine radial sort key is REQUIRED -- every octant/
//    coarse-shell key variant = 48-54 us (+18) across 3 different sort
//    pipelines (r8-r11, r14). Never touch the key again.
//  * cooperative launch / host queries in kernel_launch: BANNED (420 us).
//  * 1723 same-address atomic tail: BANNED (25-35 us).
//  * per-thread serial global-load loops without unroll: BANNED (~450cy/ld).
// Deltas this round:
//  1) reduce_kernel dispatch eliminated: knn blocks do last-block-done
//     winner reduction with TWO-LEVEL SPREAD counters (32 slots by bid&31,
//     ~54 adds each in parallel across addresses + 32 adds on one master
//     -- far from the banned same-address regime). Winner re-reduces
//     partial[] with arithmetic byte-identical to the old reduce_kernel
//     => out[0] bit-identical regardless of winner. Counters zeroed in
//     hist (earlier dispatch => race-free, re-zeroed each graph replay).
//  2) knn main scan batches 2 chunks/iter: smax is monotone non-increasing
//     so breaking on the pair's FIRST chunk is exact (<=1 extra chunk of
//     harmless work); two independent float4 loads/iter -> 2x MLP, half
//     the loop/break overhead. Insert machinery byte-identical to R0.

constexpr int K = 15;
constexpr int NBUCK = 256;
constexpr int WAVES = 4;     // waves (=vertices) per block in main kernel

__device__ __forceinline__ int bucket_of(float k2) {
    int b = (int)(k2 * 8.0f);           // 0.125-wide buckets over |p|^2 in [0,32)
    b = b > (NBUCK - 1) ? (NBUCK - 1) : b;
    return (NBUCK - 1) - b;             // bucket 0 = largest |p|
}

__global__ __launch_bounds__(256) void hist_kernel(
    const float* __restrict__ sv, int* __restrict__ blkhist,
    int* __restrict__ cnt, int N)
{
    __shared__ int h[NBUCK];
    int t = threadIdx.x;
    h[t] = 0;
    if (blockIdx.x == 0 && t < 33) cnt[t] = 0;   // completion counters
    __syncthreads();
    int i = blockIdx.x * 256 + t;
    if (i < N) {
        float x = sv[3*i], y = sv[3*i+1], z = sv[3*i+2];
        atomicAdd(&h[bucket_of(fmaf(x, x, fmaf(y, y, z*z)))], 1);
    }
    __syncthreads();
    blkhist[blockIdx.x * NBUCK + t] = h[t];   // full-row overwrite (poison-safe)
}

__global__ __launch_bounds__(256) void scan_scatter_kernel(
    const float* __restrict__ sv,
    const int*   __restrict__ blkhist,  // [nblk][NBUCK]
    float4*      __restrict__ sorted,   // [N] out: (x,y,z,bitcast(origIdx))
    float*       __restrict__ smax,     // [nb] out: |p| upper bound at pos >= j*64
    int N, int nb, int nblk)
{
    __shared__ int tmp[NBUCK];
    __shared__ int startSh[NBUCK];
    __shared__ int cursor[NBUCK];
    const int t   = threadIdx.x;
    const int blk = blockIdx.x;

    // column sums over blocks (coalesced row reads); unrolled so the L2
    // loads pipeline instead of serializing on latency
    int mine = 0, total = 0;
#pragma unroll 8
    for (int b = 0; b < nblk; ++b) {
        int v = blkhist[b * NBUCK + t];
        if (b < blk) mine += v;
        total += v;
    }
    tmp[t] = total;
    __syncthreads();
    // Kogge-Stone inclusive scan over buckets
    for (int d = 1; d < NBUCK; d <<= 1) {
        int u = (t >= d) ? tmp[t - d] : 0;
        __syncthreads();
        tmp[t] += u;
        __syncthreads();
    }
    int startv = tmp[t] - total;        // exclusive bucket start
    startSh[t] = startv;
    cursor[t]  = startv + mine;         // this block's write base per bucket
    __syncthreads();

    if (blk == 0) {
        // smax[j]: position j*64 lies in flipped bucket fb (largest fb with
        // start[fb] <= pos); all points at pos >= j*64 have original bucket
        // <= (NBUCK-1)-fb, so |p| <= sqrt(upper edge). Exact upper bound,
        // independent of within-bucket order.
        for (int j = t; j < nb; j += 256) {
            int pos = j * 64;
            int lo = 0, hi = NBUCK - 1;
            while (lo < hi) {
                int mid = (lo + hi + 1) >> 1;
                if (startSh[mid] <= pos) lo = mid; else hi = mid - 1;
            }
            int bOrig = (NBUCK - 1) - lo;
            smax[j] = sqrtf((float)(bOrig + 1) * 0.125f);
        }
    }

    int i = blk * 256 + t;
    if (i < N) {
        float x = sv[3*i], y = sv[3*i+1], z = sv[3*i+2];
        float k2 = fmaf(x, x, fmaf(y, y, z*z));
        int pos = atomicAdd(&cursor[bucket_of(k2)], 1);   // LDS atomic
        sorted[pos] = make_float4(x, y, z, __int_as_float(i));
    }
}

template<bool SORTED>
__global__ __launch_bounds__(WAVES * 64) void knn_loss_kernel(
    const float4* __restrict__ pts,   // sorted points (SORTED only)
    const float*  __restrict__ smax,  // suffix |p| upper bound per 64-block
    const float*  __restrict__ sv,    // [N,3] original scan vertices
    const float*  __restrict__ tv,    // [M,3]
    const float*  __restrict__ sn,    // [N,3]
    const float*  __restrict__ tn,    // [M,3]
    float* __restrict__ partial,      // [gridDim.x] per-block sums (no atomics)
    float* __restrict__ out,          // [1] final result (winner block writes)
    int*   __restrict__ cnt,          // [33] completion counters (nullptr=off)
    int N, int M, float invM, int nUnits)
{
    __shared__ float bsum[WAVES];
    __shared__ int winnerSh;
    const int lane = threadIdx.x & 63;
    const int w    = threadIdx.x >> 6;
    const int m    = blockIdx.x * WAVES + w;
    const bool valid = (m < M);

    float contrib = 0.0f;
    if (valid) {
        const float tvx = tv[3*m], tvy = tv[3*m+1], tvz = tv[3*m+2];
        const float tlen = sqrtf(tvx*tvx + tvy*tvy + tvz*tvz);

        // ---- bootstrap: bitonic-sort first 64 points desc by (d2, -idx) ----
        float v; int idx;
        {
            int l = (lane < N) ? lane : 0;
            float px, py, pz;
            if (SORTED) {
                float4 q = pts[l];
                px = q.x; py = q.y; pz = q.z; idx = __float_as_int(q.w);
            } else {
                px = sv[3*l]; py = sv[3*l+1]; pz = sv[3*l+2]; idx = l;
            }
            float dx = px - tvx, dy = py - tvy, dz = pz - tvz;
            v = fmaf(dx, dx, fmaf(dy, dy, dz * dz));
            if (lane >= N) { v = -1.0f; idx = 0x7FFFFFFF; }
        }
#pragma unroll
        for (int k = 2; k <= 64; k <<= 1) {
#pragma unroll
            for (int j = k >> 1; j > 0; j >>= 1) {
                float ov = __shfl_xor(v, j);
                int   oi = __shfl_xor(idx, j);
                bool up    = ((lane & k) == 0);   // descending segment
                bool lower = ((lane & j) == 0);
                bool mine  = (v > ov) || (v == ov && idx < oi); // total order
                bool keep  = lower ? (up ? mine : !mine) : (up ? !mine : mine);
                if (!keep) { v = ov; idx = oi; }
            }
        }
        // lanes 0..K-1 now hold the exact top-K of the first 64 (sorted desc)
        float eV = (lane < K) ? v : -1.0f;
        int   eI = idx;
        float thr = __shfl(v, K - 1);   // current 15th-largest d2

        // serial sorted insert, byte-identical semantics to R0
        auto insert_chunk = [&](float d2, int oi2, bool has) {
            // >= : an equal-d2 candidate with lower original idx must displace
            unsigned long long mb = __ballot(has && (d2 >= thr));
            while (mb) {
                int src = __ffsll(mb) - 1;
                mb &= mb - 1;
                float cv = __shfl(d2, src);
                int   ci = __shfl(oi2, src);
                // position = #entries strictly better than candidate
                unsigned long long bb =
                    __ballot((eV > cv) || (eV == cv && eI < ci)) & 0x7FFFull;
                int p = __popcll(bb);
                if (p < K) {   // wave-uniform
                    float uv = __shfl_up(eV, 1);
                    int   ui = __shfl_up(eI, 1);
                    if (lane < K) {
                        if (lane == p)      { eV = cv; eI = ci; }
                        else if (lane > p)  { eV = uv; eI = ui; }
                    }
                    // tighten thr NOW and prune doomed candidates
                    thr = __shfl(eV, K - 1);
                    if (mb) mb &= __ballot(d2 >= thr);
                }
            }
        };

        // ---- main scan ----
        if (SORTED) {
            // 2 chunks per iter: smax monotone non-increasing => breaking on
            // the pair's first chunk is exact; both loads issue before the
            // break check (wasted prefetch on break harmless)
            for (int ib = 64; ib < N; ib += 128) {
                int  i0 = ib + lane,      i1 = ib + 64 + lane;
                bool h0 = (i0 < N),       h1 = (i1 < N);
                float4 q0 = pts[h0 ? i0 : 0];
                float4 q1 = pts[h1 ? i1 : 0];
                float bnd = smax[ib >> 6] + tlen;      // bound for chunk pair
                if (bnd * bnd * 1.00001f < thr) break; // margin covers fp rounding
                float dx0 = q0.x - tvx, dy0 = q0.y - tvy, dz0 = q0.z - tvz;
                float d20 = fmaf(dx0, dx0, fmaf(dy0, dy0, dz0 * dz0));
                insert_chunk(d20, __float_as_int(q0.w), h0);
                if (ib + 64 < N) {
                    float dx1 = q1.x - tvx, dy1 = q1.y - tvy, dz1 = q1.z - tvz;
                    float d21 = fmaf(dx1, dx1, fmaf(dy1, dy1, dz1 * dz1));
                    insert_chunk(d21, __float_as_int(q1.w), h1);
                }
            }
        } else {
            for (int ib = 64; ib < N; ib += 64) {
                int  i   = ib + lane;
                bool has = (i < N);
                int g = has ? i : 0;
                float dx = sv[3*g] - tvx, dy = sv[3*g+1] - tvy, dz = sv[3*g+2] - tvz;
                float d2 = fmaf(dx, dx, fmaf(dy, dy, dz * dz));
                insert_chunk(d2, i, has);
            }
        }

        // ---- epilogue: argmin angle, tie-break by top-k rank (= lane) ----
        const float tnx = tn[3*m], tny = tn[3*m+1], tnz = tn[3*m+2];
        float ang = 3.0e38f;
        int myI = eI;
        if (lane < K && myI != 0x7FFFFFFF) {
            float dot = sn[3*myI]*tnx + sn[3*myI+1]*tny + sn[3*myI+2]*tnz;
            dot = fminf(1.0f, fmaxf(-1.0f, dot));
            ang = acosf(dot) * 57.29577951308232f;   // degrees, matches jnp
        }
        // entries live in lanes 0..14 -> reduce within the 16-lane group
        float ba = ang; int br = lane; int bi = myI;
#pragma unroll
        for (int s = 1; s < 16; s <<= 1) {
            float oa  = __shfl_xor(ba, s);
            int   orr = __shfl_xor(br, s);
            int   oi  = __shfl_xor(bi, s);
            bool take = (oa < ba) || (oa == ba && orr < br);
            if (take) { ba = oa; br = orr; bi = oi; }
        }
        if (lane == 0) {
            float dx = sv[3*bi]   - tvx;
            float dy = sv[3*bi+1] - tvy;
            float dz = sv[3*bi+2] - tvz;
            contrib = sqrtf(dx*dx + dy*dy + dz*dz) * invM;
        }
    }

    if (lane == 0) bsum[w] = contrib;
    __syncthreads();
    if (threadIdx.x == 0)
        partial[blockIdx.x] = bsum[0] + bsum[1] + bsum[2] + bsum[3];

    // ---- last-block-done winner reduction (two-level spread counters) ----
    if (cnt != nullptr) {
        __threadfence();                          // publish partial[]
        if (threadIdx.x == 0) {
            int s = blockIdx.x & 31;
            int nSlots = (nUnits < 32) ? nUnits : 32;
            int quota  = ((nUnits - 1 - s) >> 5) + 1;   // #blocks with bid&31==s
            int win = 0;
            int v = atomicAdd(&cnt[s], 1);        // spread: ~54 adds/address
            if (v == quota - 1) {
                __threadfence();
                int mv = atomicAdd(&cnt[32], 1);  // master: <=32 adds
                if (mv == nSlots - 1) win = 1;
            }
            winnerSh = win;
        }
        __syncthreads();
        if (winnerSh) {
            __threadfence();                      // acquire all partial[]
            // arithmetic byte-identical to the old reduce_kernel
            float s = 0.0f;
            for (int i = threadIdx.x; i < nUnits; i += 256) s += partial[i];
#pragma unroll
            for (int d = 1; d < 64; d <<= 1) s += __shfl_xor(s, d);
            if (lane == 0) bsum[w] = s;
            __syncthreads();
            if (threadIdx.x == 0)
                out[0] = bsum[0] + bsum[1] + bsum[2] + bsum[3];
        }
    }
}

__global__ __launch_bounds__(256) void reduce_kernel(   // fallback path only
    const float* __restrict__ partial, float* __restrict__ out, int n)
{
    __shared__ float sh[4];
    const int lane = threadIdx.x & 63;
    const int w    = threadIdx.x >> 6;
    float s = 0.0f;
    for (int i = threadIdx.x; i < n; i += 256) s += partial[i];
#pragma unroll
    for (int d = 1; d < 64; d <<= 1) s += __shfl_xor(s, d);
    if (lane == 0) sh[w] = s;
    __syncthreads();
    if (threadIdx.x == 0) out[0] = sh[0] + sh[1] + sh[2] + sh[3];
}

extern "C" void kernel_launch(void* const* d_in, const int* in_sizes, int n_in,
                              void* d_out, int out_size, void* d_ws, size_t ws_size,
                              hipStream_t stream) {
    const float* sv = (const float*)d_in[0];   // scan_vertices   [1,N,3]
    const float* tv = (const float*)d_in[1];   // template_vertices [1,M,3]
    const float* sn = (const float*)d_in[2];   // scan_normals    [N,3]
    const float* tn = (const float*)d_in[3];   // template_normals [M,3]
    // d_in[4] = K_knn (fixed 15, compile-time)

    int N = in_sizes[0] / 3;
    int M = in_sizes[1] / 3;
    int nb = (N + 63) / 64;
    float* out = (float*)d_out;
    float invM = 1.0f / (float)M;
    int grid  = (M + WAVES - 1) / WAVES;       // 1723
    int nblk  = (N + 255) / 256;               // 79

    // d_ws: [sorted N float4][smax nb][blkhist nblk*256][partial grid][cnt 33]
    size_t offSorted  = 0;
    size_t offSmax    = offSorted + (size_t)N * sizeof(float4);
    size_t offHist    = (offSmax + (size_t)nb * sizeof(float) + 15) & ~(size_t)15;
    size_t offPartial = offHist + (size_t)nblk * NBUCK * sizeof(int);
    size_t offCnt     = (offPartial + (size_t)grid * sizeof(float) + 15) & ~(size_t)15;
    size_t need       = offCnt + 33 * sizeof(int);

    if (ws_size >= need) {
        float4* sorted  = (float4*)((char*)d_ws + offSorted);
        float*  smaxp   = (float*) ((char*)d_ws + offSmax);
        int*    blkhist = (int*)   ((char*)d_ws + offHist);
        float*  partial = (float*) ((char*)d_ws + offPartial);
        int*    cnt     = (int*)   ((char*)d_ws + offCnt);

        hist_kernel        <<<nblk, 256, 0, stream>>>(sv, blkhist, cnt, N);
        scan_scatter_kernel<<<nblk, 256, 0, stream>>>(sv, blkhist, sorted,
                                                      smaxp, N, nb, nblk);
        knn_loss_kernel<true><<<grid, WAVES * 64, 0, stream>>>(
            sorted, smaxp, sv, tv, sn, tn, partial, out, cnt, N, M, invM, grid);
    } else if (ws_size >= (size_t)grid * sizeof(float)) {
        float* partial = (float*)d_ws;
        knn_loss_kernel<false><<<grid, WAVES * 64, 0, stream>>>(
            nullptr, nullptr, sv, tv, sn, tn, partial, out, nullptr,
            N, M, invM, grid);
        reduce_kernel<<<1, 256, 0, stream>>>(partial, out, grid);
    }
}